// Round 1
// baseline (500.967 us; speedup 1.0000x reference)
//
#include <hip/hip_runtime.h>
#include <math.h>

// Problem constants (from reference setup_inputs)
#define NROWS 65536
#define DDIM  1024
#define NEXP  64      // experts
#define NC    128     // combined output cols: [0..63]=route logits, [64..127]=noise logits
#define BM    128     // rows per block
#define BK    32      // K chunk
#define XS_LD 36      // xs leading dim (pad: 16B-aligned rows, conflict-free reads w/ m=r*16+rg)
#define WS_LD 132     // ws leading dim (pad: 2-way bank alias only = free)

// jax.nn.softplus(x) == logaddexp(x, 0) == max(x,0) + log1p(exp(-|x|))
__device__ __forceinline__ float softplus_f(float x) {
    return fmaxf(x, 0.0f) + log1pf(expf(-fabsf(x)));
}

// wt[d*128 + e2] = (e2<64 ? w_route[e2][d] : w_noise[e2-64][d])
__global__ void __launch_bounds__(256) transpose_w_kernel(
        const float* __restrict__ wr, const float* __restrict__ wn,
        float* __restrict__ wt) {
    int idx = blockIdx.x * 256 + threadIdx.x;   // 0..131071
    int d  = idx >> 7;
    int e2 = idx & 127;
    float v = (e2 < NEXP) ? wr[e2 * DDIM + d] : wn[(e2 - NEXP) * DDIM + d];
    wt[idx] = v;
}

__global__ void __launch_bounds__(256, 2) router_kernel(
        const float* __restrict__ x, const float* __restrict__ wt,
        const float* __restrict__ eps, float* __restrict__ out) {
    // Union'd LDS: main loop uses xs[128][36] + ws[32][132] = 35328 B;
    // epilogue reuses the same region as cand[128][33] float2 = 33792 B.
    __shared__ __align__(16) char smem_raw[BM * XS_LD * 4 + BK * WS_LD * 4];
    __shared__ float4 rowout[BM];   // (p0, p1, i0 bits, i1 bits)

    float* xs = (float*)smem_raw;           // [BM][XS_LD]
    float* ws = xs + BM * XS_LD;            // [BK][WS_LD]

    const int tid = threadIdx.x;
    const int rg  = tid >> 4;     // 0..15  (in-wave: 0..3)
    const int cg  = tid & 15;     // 0..15  -> experts cg*4 .. cg*4+3
    const int blockM = blockIdx.x * BM;

    // acc[r][c]: rows m = r*16+rg; c 0..3 = route logits for experts cg*4+c,
    //            c 4..7 = noise logits for the same experts.
    float acc[8][8];
#pragma unroll
    for (int r = 0; r < 8; ++r)
#pragma unroll
        for (int c = 0; c < 8; ++c) acc[r][c] = 0.0f;

    for (int k0 = 0; k0 < DDIM; k0 += BK) {
        // --- stage x tile: 128 rows x 32 k (4 float4 per thread, coalesced) ---
#pragma unroll
        for (int i = 0; i < 4; ++i) {
            int idx = i * 256 + tid;           // 0..1023 float4s
            int row = idx >> 3;                // 0..127
            int kq  = (idx & 7) << 2;          // 0,4,..28
            float4 v = *(const float4*)&x[(size_t)(blockM + row) * DDIM + k0 + kq];
            *(float4*)&xs[row * XS_LD + kq] = v;
        }
        // --- stage w tile: contiguous 16 KB chunk of wt ---
#pragma unroll
        for (int i = 0; i < 4; ++i) {
            int idx = i * 256 + tid;           // 0..1023 float4s
            int kk  = idx >> 5;                // 0..31
            int nq  = (idx & 31) << 2;         // 0..124
            float4 v = *(const float4*)&wt[(size_t)(k0 + kk) * NC + nq];
            *(float4*)&ws[kk * WS_LD + nq] = v;
        }
        __syncthreads();

#pragma unroll
        for (int kk = 0; kk < BK; kk += 4) {
            float4 xf[8];
#pragma unroll
            for (int r = 0; r < 8; ++r)
                xf[r] = *(const float4*)&xs[(r * 16 + rg) * XS_LD + kk];
#pragma unroll
            for (int q = 0; q < 4; ++q) {
                float4 wl  = *(const float4*)&ws[(kk + q) * WS_LD + cg * 4];
                float4 wn4 = *(const float4*)&ws[(kk + q) * WS_LD + NEXP + cg * 4];
#pragma unroll
                for (int r = 0; r < 8; ++r) {
                    float xv = (q == 0) ? xf[r].x : (q == 1) ? xf[r].y
                             : (q == 2) ? xf[r].z : xf[r].w;
                    acc[r][0] = fmaf(xv, wl.x,  acc[r][0]);
                    acc[r][1] = fmaf(xv, wl.y,  acc[r][1]);
                    acc[r][2] = fmaf(xv, wl.z,  acc[r][2]);
                    acc[r][3] = fmaf(xv, wl.w,  acc[r][3]);
                    acc[r][4] = fmaf(xv, wn4.x, acc[r][4]);
                    acc[r][5] = fmaf(xv, wn4.y, acc[r][5]);
                    acc[r][6] = fmaf(xv, wn4.z, acc[r][6]);
                    acc[r][7] = fmaf(xv, wn4.w, acc[r][7]);
                }
            }
        }
        __syncthreads();
    }

    // ---------------- Epilogue ----------------
    // cand[m][2*cg + s] = (value, index-bits), row stride 33 float2 (pad)
    float2* cand = (float2*)smem_raw;

#pragma unroll
    for (int r = 0; r < 8; ++r) {
        int m = r * 16 + rg;
        int n = blockM + m;
        float4 ep = *(const float4*)&eps[(size_t)n * NEXP + cg * 4];
        const float* epp = (const float*)&ep;
        float v0 = -INFINITY, v1 = -INFINITY;
        int   i0 = 1 << 20,   i1 = 1 << 20;
#pragma unroll
        for (int j = 0; j < 4; ++j) {
            float nz = fmaf(epp[j], softplus_f(acc[r][4 + j]), acc[r][j]);
            int e = cg * 4 + j;
            bool b0 = (nz > v0) || (nz == v0 && e < i0);
            bool b1 = (nz > v1) || (nz == v1 && e < i1);
            if (b0) { v1 = v0; i1 = i0; v0 = nz; i0 = e; }
            else if (b1) { v1 = nz; i1 = e; }
        }
        cand[m * 33 + cg * 2    ] = make_float2(v0, __int_as_float(i0));
        cand[m * 33 + cg * 2 + 1] = make_float2(v1, __int_as_float(i1));
    }
    __syncthreads();

    // one thread per row: merge 32 candidates with exact lax.top_k semantics
    if (tid < BM) {
        int m = tid;
        float v0 = -INFINITY, v1 = -INFINITY;
        int   i0 = 1 << 20,   i1 = 1 << 20;
#pragma unroll 4
        for (int c = 0; c < 32; ++c) {
            float2 cv = cand[m * 33 + c];
            float v = cv.x;
            int   e = __float_as_int(cv.y);
            bool b0 = (v > v0) || (v == v0 && e < i0);
            bool b1 = (v > v1) || (v == v1 && e < i1);
            if (b0) { v1 = v0; i1 = i0; v0 = v; i0 = e; }
            else if (b1) { v1 = v; i1 = e; }
        }
        // softmax over [v0, v1], v0 >= v1
        float e1  = expf(v1 - v0);
        float inv = 1.0f / (1.0f + e1);
        rowout[m] = make_float4(inv, e1 * inv, __int_as_float(i0), __int_as_float(i1));
        // indices output (stored as float values in the concatenated out buffer)
        int n = blockM + m;
        float* idx_out = out + (size_t)NROWS * NEXP;
        idx_out[n * 2    ] = (float)i0;
        idx_out[n * 2 + 1] = (float)i1;
    }
    __syncthreads();

    // coalesced scatter-write of the [128][64] output tile
#pragma unroll
    for (int i = 0; i < 8; ++i) {
        int f  = i * 256 + tid;        // float4 id, 0..2047
        int m  = f >> 4;               // row in tile
        int c4 = (f & 15) << 2;        // starting col
        float4 ro = rowout[m];
        int i0 = __float_as_int(ro.z);
        int i1 = __float_as_int(ro.w);
        float4 o;
        float* op = (float*)&o;
#pragma unroll
        for (int j = 0; j < 4; ++j) {
            int col = c4 + j;
            op[j] = (col == i0) ? ro.x : (col == i1) ? ro.y : 0.0f;
        }
        *(float4*)&out[(size_t)(blockM + m) * NEXP + c4] = o;
    }
}

extern "C" void kernel_launch(void* const* d_in, const int* in_sizes, int n_in,
                              void* d_out, int out_size, void* d_ws, size_t ws_size,
                              hipStream_t stream) {
    const float* x   = (const float*)d_in[0];
    const float* wr  = (const float*)d_in[1];
    const float* wn  = (const float*)d_in[2];
    const float* eps = (const float*)d_in[3];
    float* out = (float*)d_out;
    float* wt  = (float*)d_ws;   // 1024*128 floats = 512 KB scratch

    transpose_w_kernel<<<dim3(512), dim3(256), 0, stream>>>(wr, wn, wt);
    router_kernel<<<dim3(NROWS / BM), dim3(256), 0, stream>>>(x, wt, eps, out);
}

// Round 2
// 432.953 us; speedup vs baseline: 1.1571x; 1.1571x over previous
//
#include <hip/hip_runtime.h>
#include <math.h>

// Problem constants
#define NROWS 65536
#define DDIM  1024
#define NEXP  64
#define NC    128     // combined cols: 0..63 route, 64..127 noise
#define BM    128     // rows per block
#define LDX   72      // x LDS leading dim (bf16 elements; 144 B rows, 16B-aligned frags)
#define WCHUNK 12288  // shorts per k32-chunk of packed w: 3 splits * 128 n * 32 k

typedef short bf16x8 __attribute__((ext_vector_type(8)));
typedef float f32x4  __attribute__((ext_vector_type(4)));

// exact 3-way bf16 split: x == h + m + l (+ O(2^-27 x))
__device__ __forceinline__ void split3(float x, unsigned short& h,
                                       unsigned short& m, unsigned short& l) {
    unsigned u = __float_as_uint(x);
    unsigned r = u + 0x7FFFu + ((u >> 16) & 1u);
    h = (unsigned short)(r >> 16);
    float hf = __uint_as_float(r & 0xFFFF0000u);
    float r1 = x - hf;
    unsigned u2 = __float_as_uint(r1);
    unsigned r2 = u2 + 0x7FFFu + ((u2 >> 16) & 1u);
    m = (unsigned short)(r2 >> 16);
    float mf = __uint_as_float(r2 & 0xFFFF0000u);
    float r3 = r1 - mf;
    unsigned u3 = __float_as_uint(r3);
    unsigned r4 = u3 + 0x7FFFu + ((u3 >> 16) & 1u);
    l = (unsigned short)(r4 >> 16);
}

__device__ __forceinline__ float softplus_f(float x) {
    return fmaxf(x, 0.0f) + log1pf(expf(-fabsf(x)));
}

// Pack weights: wp[chunk][split][n][32] bf16, n = 0..63 route, 64..127 noise.
// B-frag for col n, k-block q is then 16 contiguous bytes at n*64 + q*16.
__global__ void __launch_bounds__(256) prep_w_kernel(
        const float* __restrict__ wr, const float* __restrict__ wn,
        short* __restrict__ wp) {
    int idx = blockIdx.x * 256 + threadIdx.x;   // 0..131071
    int n = idx >> 10;
    int k = idx & 1023;
    float v = (n < NEXP) ? wr[n * DDIM + k] : wn[(n - NEXP) * DDIM + k];
    unsigned short h, m, l;
    split3(v, h, m, l);
    int base = (k >> 5) * WCHUNK + n * 32 + (k & 31);
    wp[base]        = (short)h;
    wp[base + 4096] = (short)m;
    wp[base + 8192] = (short)l;
}

__global__ void __launch_bounds__(256, 2) router_kernel(
        const float* __restrict__ x, const short* __restrict__ wp,
        const float* __restrict__ eps, float* __restrict__ out) {
    // xs: 3 split planes of [128][72] bf16 = 55296 B. Epilogue reuses the
    // same region as noisy[128][66] fp32 = 33792 B.
    __shared__ __align__(16) char smem[3 * BM * LDX * 2];
    __shared__ float4 rowout[BM];
    short* xs = (short*)smem;

    const int tid    = threadIdx.x;
    const int lane   = tid & 63;
    const int wave   = tid >> 6;
    const int lane16 = lane & 15;
    const int quad   = lane >> 4;
    const int wm     = wave >> 1;         // m-half: rows wm*64..
    const int wn2    = wave & 1;          // n-half: route cols wn2*32..
    const int m0     = wm * 64;
    const int blockM = blockIdx.x * BM;

    f32x4 acc[4][4];   // [mi][ni]; ni 0,1 = route cols wn2*32+{0,16}; ni 2,3 = noise
#pragma unroll
    for (int a = 0; a < 4; ++a)
#pragma unroll
        for (int b = 0; b < 4; ++b) acc[a][b] = (f32x4)0.0f;

#pragma unroll 1
    for (int kc = 0; kc < DDIM / 64; ++kc) {
        // ---- stage x tile [128][64] fp32 -> 3 bf16 LDS planes ----
#pragma unroll
        for (int it = 0; it < 8; ++it) {
            int idx = it * 256 + tid;          // 0..2047 float4s
            int row = idx >> 4;
            int kq  = (idx & 15) << 2;
            float4 v = *(const float4*)&x[(size_t)(blockM + row) * DDIM + kc * 64 + kq];
            const float* vp = (const float*)&v;
            unsigned short hs[3][4];
#pragma unroll
            for (int j = 0; j < 4; ++j) split3(vp[j], hs[0][j], hs[1][j], hs[2][j]);
#pragma unroll
            for (int s = 0; s < 3; ++s) {
                uint2 p;
                p.x = (unsigned)hs[s][0] | ((unsigned)hs[s][1] << 16);
                p.y = (unsigned)hs[s][2] | ((unsigned)hs[s][3] << 16);
                *(uint2*)(xs + s * (BM * LDX) + row * LDX + kq) = p;
            }
        }
        __syncthreads();

#pragma unroll
        for (int sub = 0; sub < 2; ++sub) {
            const short* wpc = wp + (size_t)(kc * 2 + sub) * WCHUNK;
            bf16x8 Af[3][4], Bf[3][4];
#pragma unroll
            for (int s = 0; s < 3; ++s) {
#pragma unroll
                for (int mi = 0; mi < 4; ++mi)
                    Af[s][mi] = *(const bf16x8*)(xs + s * (BM * LDX) +
                                 (m0 + mi * 16 + lane16) * LDX + sub * 32 + quad * 8);
#pragma unroll
                for (int ni = 0; ni < 4; ++ni) {
                    int col = wn2 * 32 + (ni & 1) * 16 + (ni >> 1) * 64 + lane16;
                    Bf[s][ni] = *(const bf16x8*)(wpc + s * 4096 + col * 32 + quad * 8);
                }
            }
#pragma unroll
            for (int mi = 0; mi < 4; ++mi)
#pragma unroll
                for (int ni = 0; ni < 4; ++ni) {
                    f32x4 c = acc[mi][ni];
                    c = __builtin_amdgcn_mfma_f32_16x16x32_bf16(Af[2][mi], Bf[0][ni], c, 0, 0, 0);
                    c = __builtin_amdgcn_mfma_f32_16x16x32_bf16(Af[0][mi], Bf[2][ni], c, 0, 0, 0);
                    c = __builtin_amdgcn_mfma_f32_16x16x32_bf16(Af[1][mi], Bf[1][ni], c, 0, 0, 0);
                    c = __builtin_amdgcn_mfma_f32_16x16x32_bf16(Af[1][mi], Bf[0][ni], c, 0, 0, 0);
                    c = __builtin_amdgcn_mfma_f32_16x16x32_bf16(Af[0][mi], Bf[1][ni], c, 0, 0, 0);
                    c = __builtin_amdgcn_mfma_f32_16x16x32_bf16(Af[0][mi], Bf[0][ni], c, 0, 0, 0);
                    acc[mi][ni] = c;
                }
        }
        __syncthreads();
    }

    // ---------------- Epilogue ----------------
    // C-frag layout: row = quad*4 + v, col = lane16  [m89]
    float* noisy = (float*)smem;   // [128][66]
#pragma unroll
    for (int mi = 0; mi < 4; ++mi)
#pragma unroll
        for (int ni = 0; ni < 2; ++ni)
#pragma unroll
            for (int v = 0; v < 4; ++v) {
                int row = m0 + mi * 16 + quad * 4 + v;            // local
                int col = wn2 * 32 + ni * 16 + lane16;            // expert
                float logit = acc[mi][ni][v];
                float nslg  = acc[mi][ni + 2][v];
                float ev = eps[(size_t)(blockM + row) * NEXP + col];
                noisy[row * 66 + col] = fmaf(ev, softplus_f(nslg), logit);
            }
    __syncthreads();

    // top-2 per row: 2 threads/row scan 32 cols each, merge via shfl_xor(1)
    {
        int row  = tid >> 1;
        int half = tid & 1;
        float v0 = -INFINITY, v1 = -INFINITY;
        int   i0 = 1 << 20,   i1 = 1 << 20;
#pragma unroll 8
        for (int j = 0; j < 32; ++j) {
            int col = half * 32 + j;
            float v = noisy[row * 66 + col];
            if (v > v0) { v1 = v0; i1 = i0; v0 = v; i0 = col; }
            else if (v > v1) { v1 = v; i1 = col; }
        }
        float bv0 = __shfl_xor(v0, 1, 64);
        int   bi0 = __shfl_xor(i0, 1, 64);
        float bv1 = __shfl_xor(v1, 1, 64);
        int   bi1 = __shfl_xor(i1, 1, 64);
        if (half == 0) {
            // partner cols are strictly higher -> strict '>' keeps lower index on ties
            if (bv0 > v0) { v1 = v0; i1 = i0; v0 = bv0; i0 = bi0; }
            else if (bv0 > v1) { v1 = bv0; i1 = bi0; }
            if (bv1 > v1) { v1 = bv1; i1 = bi1; }
            float e1  = expf(v1 - v0);
            float inv = 1.0f / (1.0f + e1);
            rowout[row] = make_float4(inv, e1 * inv, __int_as_float(i0), __int_as_float(i1));
            int n = blockM + row;
            float* idx_out = out + (size_t)NROWS * NEXP;
            idx_out[n * 2]     = (float)i0;
            idx_out[n * 2 + 1] = (float)i1;
        }
    }
    __syncthreads();

    // coalesced [128][64] output tile write
#pragma unroll
    for (int it = 0; it < 8; ++it) {
        int f  = it * 256 + tid;
        int m  = f >> 4;
        int c4 = (f & 15) << 2;
        float4 ro = rowout[m];
        int i0 = __float_as_int(ro.z);
        int i1 = __float_as_int(ro.w);
        float4 o;
        float* op = (float*)&o;
#pragma unroll
        for (int j = 0; j < 4; ++j) {
            int col = c4 + j;
            op[j] = (col == i0) ? ro.x : (col == i1) ? ro.y : 0.0f;
        }
        *(float4*)&out[(size_t)(blockM + m) * NEXP + c4] = o;
    }
}

extern "C" void kernel_launch(void* const* d_in, const int* in_sizes, int n_in,
                              void* d_out, int out_size, void* d_ws, size_t ws_size,
                              hipStream_t stream) {
    const float* x   = (const float*)d_in[0];
    const float* wr  = (const float*)d_in[1];
    const float* wn  = (const float*)d_in[2];
    const float* eps = (const float*)d_in[3];
    float* out = (float*)d_out;
    short* wp  = (short*)d_ws;   // 32 chunks * 12288 shorts = 1.5 MB scratch

    prep_w_kernel<<<dim3(512), dim3(256), 0, stream>>>(wr, wn, wp);
    router_kernel<<<dim3(NROWS / BM), dim3(256), 0, stream>>>(x, wp, eps, out);
}

// Round 3
// 419.803 us; speedup vs baseline: 1.1933x; 1.0313x over previous
//
#include <hip/hip_runtime.h>
#include <math.h>

// Problem constants
#define NROWS 65536
#define DDIM  1024
#define NEXP  64
#define BM    64      // rows per block
#define BK    32      // K chunk (== one MFMA K)
#define LDX   40      // split-plane leading dim in bf16 elements (80 B rows)
#define PLANE (BM * LDX)          // 2560 shorts per split plane
#define WCHUNK 12288  // shorts per k32-chunk of packed w: 3 splits * 128 n * 32 k

typedef short bf16x8 __attribute__((ext_vector_type(8)));
typedef float f32x4  __attribute__((ext_vector_type(4)));

// exact-ish 3-way bf16 split, round-to-nearest (used in one-time w prep)
__device__ __forceinline__ void split3(float x, unsigned short& h,
                                       unsigned short& m, unsigned short& l) {
    unsigned u = __float_as_uint(x);
    unsigned r = u + 0x7FFFu + ((u >> 16) & 1u);
    h = (unsigned short)(r >> 16);
    float hf = __uint_as_float(r & 0xFFFF0000u);
    float r1 = x - hf;
    unsigned u2 = __float_as_uint(r1);
    unsigned r2 = u2 + 0x7FFFu + ((u2 >> 16) & 1u);
    m = (unsigned short)(r2 >> 16);
    float mf = __uint_as_float(r2 & 0xFFFF0000u);
    float r3 = r1 - mf;
    unsigned u3 = __float_as_uint(r3);
    unsigned r4 = u3 + 0x7FFFu + ((u3 >> 16) & 1u);
    l = (unsigned short)(r4 >> 16);
}

// cheap truncation split for the hot x path: x = h + m + l + O(2^-24 x)
__device__ __forceinline__ void split3t(float x, unsigned& h, unsigned& m, unsigned& l) {
    unsigned u = __float_as_uint(x);
    h = u >> 16;
    float r1 = x - __uint_as_float(u & 0xFFFF0000u);
    unsigned u2 = __float_as_uint(r1);
    m = u2 >> 16;
    float r2 = r1 - __uint_as_float(u2 & 0xFFFF0000u);
    l = __float_as_uint(r2) >> 16;
}

__device__ __forceinline__ float softplus_f(float x) {
    return fmaxf(x, 0.0f) + log1pf(expf(-fabsf(x)));
}

// Pack weights: wp[chunk][split][n][32] bf16, n = 0..63 route, 64..127 noise.
__global__ void __launch_bounds__(256) prep_w_kernel(
        const float* __restrict__ wr, const float* __restrict__ wn,
        short* __restrict__ wp) {
    int idx = blockIdx.x * 256 + threadIdx.x;   // 0..131071
    int n = idx >> 10;
    int k = idx & 1023;
    float v = (n < NEXP) ? wr[n * DDIM + k] : wn[(n - NEXP) * DDIM + k];
    unsigned short h, m, l;
    split3(v, h, m, l);
    int base = (k >> 5) * WCHUNK + n * 32 + (k & 31);
    wp[base]        = (short)h;
    wp[base + 4096] = (short)m;
    wp[base + 8192] = (short)l;
}

__device__ __forceinline__ void stage_split(float4 v, short* plane, int row, int kq) {
    const float* vp = (const float*)&v;
    unsigned hs[3][4];
#pragma unroll
    for (int j = 0; j < 4; ++j) split3t(vp[j], hs[0][j], hs[1][j], hs[2][j]);
#pragma unroll
    for (int s = 0; s < 3; ++s) {
        uint2 p;
        p.x = (hs[s][0] & 0xFFFFu) | (hs[s][1] << 16);
        p.y = (hs[s][2] & 0xFFFFu) | (hs[s][3] << 16);
        *(uint2*)(plane + s * PLANE + row * LDX + kq) = p;
    }
}

__device__ __forceinline__ void top2_merge(float& v0, int& i0, float& v1, int& i1,
                                           float pv0, int pi0, float pv1, int pi1) {
    bool t0 = (pv0 > v0) || (pv0 == v0 && pi0 < i0);
    if (t0) {
        bool t1 = (v0 > pv1) || (v0 == pv1 && i0 < pi1);
        v1 = t1 ? v0 : pv1; i1 = t1 ? i0 : pi1;
        v0 = pv0; i0 = pi0;
    } else {
        bool t1 = (pv0 > v1) || (pv0 == v1 && pi0 < i1);
        if (t1) { v1 = pv0; i1 = pi0; }
    }
}

__global__ void __launch_bounds__(256, 4) router_kernel(
        const float* __restrict__ x, const short* __restrict__ wp,
        const float* __restrict__ eps, float* __restrict__ out) {
    // Double-buffered split planes: 2 bufs x 3 splits x [64][40] bf16 = 30720 B.
    // Epilogue reuses the same region as noisy[64][66] fp32 = 16896 B.
    __shared__ __align__(16) char smem[2 * 3 * PLANE * 2];
    __shared__ float4 rowout[BM];
    short* xs = (short*)smem;

    const int tid    = threadIdx.x;
    const int lane   = tid & 63;
    const int wv     = tid >> 6;      // wave 0..3 -> col group
    const int lane16 = lane & 15;
    const int quad   = lane >> 4;
    const int blockM = blockIdx.x * BM;

    // staging coords: thread covers (srow0, skq) and (srow0+32, skq)
    const int srow0 = tid >> 3;           // 0..31
    const int skq   = (tid & 7) << 2;     // 0,4,..28
    const float* xp0 = x + (size_t)(blockM + srow0) * DDIM + skq;
    const float* xp1 = xp0 + (size_t)32 * DDIM;

    // wave's expert columns: route col_r, noise col_r+64 in packed w
    const int col_r = wv * 16 + lane16;

    f32x4 acc[4][2];   // [mi][0]=route, [1]=noise
#pragma unroll
    for (int a = 0; a < 4; ++a) { acc[a][0] = (f32x4)0.0f; acc[a][1] = (f32x4)0.0f; }

    float4 xv0 = *(const float4*)xp0;
    float4 xv1 = *(const float4*)xp1;

#pragma unroll 2
    for (int kc = 0; kc < DDIM / BK; ++kc) {
        short* plane = xs + (kc & 1) * 3 * PLANE;
        const short* wpc = wp + (size_t)kc * WCHUNK;

        // B fragments for this kc (L2-hot; issued before split phase hides latency)
        bf16x8 Bf[3][2];
#pragma unroll
        for (int s = 0; s < 3; ++s) {
            Bf[s][0] = *(const bf16x8*)(wpc + s * 4096 + col_r * 32 + quad * 8);
            Bf[s][1] = *(const bf16x8*)(wpc + s * 4096 + (col_r + 64) * 32 + quad * 8);
        }

        // split current x chunk into 3 bf16 planes
        stage_split(xv0, plane, srow0,      skq);
        stage_split(xv1, plane, srow0 + 32, skq);
        __syncthreads();

        // prefetch next chunk's x (hidden behind the MFMA block below)
        if (kc < DDIM / BK - 1) {
            xv0 = *(const float4*)(xp0 + (kc + 1) * BK);
            xv1 = *(const float4*)(xp1 + (kc + 1) * BK);
        }

#pragma unroll
        for (int mi = 0; mi < 4; ++mi) {
            bf16x8 Af[3];
#pragma unroll
            for (int s = 0; s < 3; ++s)
                Af[s] = *(const bf16x8*)(plane + s * PLANE +
                          (mi * 16 + lane16) * LDX + quad * 8);
#pragma unroll
            for (int ni = 0; ni < 2; ++ni) {
                f32x4 c = acc[mi][ni];
                // small-terms-first accumulation: hl, lh, mm, mh, hm, hh
                c = __builtin_amdgcn_mfma_f32_16x16x32_bf16(Af[2], Bf[0][ni], c, 0, 0, 0);
                c = __builtin_amdgcn_mfma_f32_16x16x32_bf16(Af[0], Bf[2][ni], c, 0, 0, 0);
                c = __builtin_amdgcn_mfma_f32_16x16x32_bf16(Af[1], Bf[1][ni], c, 0, 0, 0);
                c = __builtin_amdgcn_mfma_f32_16x16x32_bf16(Af[1], Bf[0][ni], c, 0, 0, 0);
                c = __builtin_amdgcn_mfma_f32_16x16x32_bf16(Af[0], Bf[1][ni], c, 0, 0, 0);
                c = __builtin_amdgcn_mfma_f32_16x16x32_bf16(Af[0], Bf[0][ni], c, 0, 0, 0);
                acc[mi][ni] = c;
            }
        }
        // no second barrier: next iteration's writes go to the other buffer, and
        // the pre-barrier lgkmcnt(0) drain at kc+1 protects buf reuse at kc+2.
    }
    __syncthreads();   // protect smem reuse (noisy overlaps plane buffers)

    // ---------------- Epilogue ----------------
    // C-frag: row = quad*4 + v, col = lane16  [verified]
    float* noisy = (float*)smem;   // [64][66]
#pragma unroll
    for (int mi = 0; mi < 4; ++mi)
#pragma unroll
        for (int v = 0; v < 4; ++v) {
            int row = mi * 16 + quad * 4 + v;
            float ev = eps[(size_t)(blockM + row) * NEXP + col_r];
            noisy[row * 66 + col_r] =
                fmaf(ev, softplus_f(acc[mi][1][v]), acc[mi][0][v]);
        }
    __syncthreads();

    // top-2: 4 threads/row scan 16 cols each, merge via shfl_xor(1), shfl_xor(2)
    {
        int row = tid >> 2;
        int sub = tid & 3;
        float v0 = -INFINITY, v1 = -INFINITY;
        int   i0 = 1 << 20,   i1 = 1 << 20;
#pragma unroll
        for (int j = 0; j < 16; ++j) {
            int col = sub * 16 + j;
            float v = noisy[row * 66 + col];
            if (v > v0) { v1 = v0; i1 = i0; v0 = v; i0 = col; }
            else if (v > v1) { v1 = v; i1 = col; }
        }
#pragma unroll
        for (int d = 1; d <= 2; d <<= 1) {
            float pv0 = __shfl_xor(v0, d, 64);
            int   pi0 = __shfl_xor(i0, d, 64);
            float pv1 = __shfl_xor(v1, d, 64);
            int   pi1 = __shfl_xor(i1, d, 64);
            top2_merge(v0, i0, v1, i1, pv0, pi0, pv1, pi1);
        }
        if (sub == 0) {
            float e1  = expf(v1 - v0);
            float inv = 1.0f / (1.0f + e1);
            rowout[row] = make_float4(inv, e1 * inv,
                                      __int_as_float(i0), __int_as_float(i1));
            float* idx_out = out + (size_t)NROWS * NEXP;
            *(float2*)&idx_out[(size_t)(blockM + row) * 2] =
                make_float2((float)i0, (float)i1);
        }
    }
    __syncthreads();

    // coalesced [64][64] output tile write
#pragma unroll
    for (int it = 0; it < 4; ++it) {
        int f  = it * 256 + tid;       // float4 id 0..1023
        int m  = f >> 4;
        int c4 = (f & 15) << 2;
        float4 ro = rowout[m];
        int i0 = __float_as_int(ro.z);
        int i1 = __float_as_int(ro.w);
        float4 o;
        float* op = (float*)&o;
#pragma unroll
        for (int j = 0; j < 4; ++j) {
            int col = c4 + j;
            op[j] = (col == i0) ? ro.x : (col == i1) ? ro.y : 0.0f;
        }
        *(float4*)&out[(size_t)(blockM + m) * NEXP + c4] = o;
    }
}

extern "C" void kernel_launch(void* const* d_in, const int* in_sizes, int n_in,
                              void* d_out, int out_size, void* d_ws, size_t ws_size,
                              hipStream_t stream) {
    const float* x   = (const float*)d_in[0];
    const float* wr  = (const float*)d_in[1];
    const float* wn  = (const float*)d_in[2];
    const float* eps = (const float*)d_in[3];
    float* out = (float*)d_out;
    short* wp  = (short*)d_ws;   // 32 chunks * 12288 shorts = 1.5 MB scratch

    prep_w_kernel<<<dim3(512), dim3(256), 0, stream>>>(wr, wn, wp);
    router_kernel<<<dim3(NROWS / BM), dim3(256), 0, stream>>>(x, wp, eps, out);
}